// Round 20
// baseline (204.190 us; speedup 1.0000x reference)
//
#include <hip/hip_runtime.h>
#include <hip/hip_bf16.h>
#include <stdint.h>

#define R_ 8
#define N_ 8192
#define D_ 2048
#define A_ 128
#define J_ 1024          // R_*A_
#define LN_EPS 1e-5f

typedef __attribute__((ext_vector_type(8))) short bf16x8;   // 8 bf16 in 4 VGPRs
typedef __attribute__((ext_vector_type(4))) float f32x4;

__device__ inline ushort f2bf(float f) {
    union { float f; uint32_t u; } v; v.f = f;
    uint32_t u = v.u;
    return (ushort)((u + 0x7fffu + ((u >> 16) & 1u)) >> 16);   // RNE
}
__device__ inline float bf2f(ushort u) {
    union { uint32_t u; float f; } v; v.u = ((uint32_t)u) << 16;
    return v.f;
}

// ---------------------------------------------------------------------------
// k1 (k_lnx): 2048 blocks, 1:1 interleave. Even bid: 8-row x-group; odd: W-col.
//   x-group block: (1) thread's fixed-column ln_w/ln_b for ALL 8 routers
//   loaded ONCE into 64 VGPRs as bf16 (gamma=1/beta=0: exact) — kills the
//   8 B-L2-read-per-4 B-written param stream of the 1-row version (1.07 GiB
//   -> 134 MiB); (2) batch-read 8 rows, per-row shfl reduce, per-row sm
//   slots -> ONE barrier; (3) barrier-free store phase: xhat (plain, L2/L3
//   for k2) + 64 NT 1 KB-contiguous new_x row-segments — acks never drained.
//   W-col block: weight-LN of column j -> Bt (K-major bf16) + cvec.
// ---------------------------------------------------------------------------
__global__ __launch_bounds__(256) void k_lnx(
    const float* __restrict__ x,
    const float* __restrict__ W,
    const float* __restrict__ ln_w,
    const float* __restrict__ ln_b,
    const float* __restrict__ rw_w,
    const float* __restrict__ rw_b,
    const float* __restrict__ rbias,
    ushort* __restrict__ xhat,
    ushort* __restrict__ Bt,
    float* __restrict__ cvec,
    float* __restrict__ new_x)
{
    __shared__ float sm[64];
    const int t = threadIdx.x;

    if ((blockIdx.x & 1) == 0) {
        const int g  = blockIdx.x >> 1;      // 0..1023
        const int n0 = g * 8;
        const int wid = t >> 6;

        // LN params -> bf16 regs (cols t*4..t*4+3 and 1024+t*4..+3)
        ushort4 wreg[8][2], breg[8][2];
        #pragma unroll
        for (int r = 0; r < 8; ++r) {
            const float4 w0 = *(const float4*)(ln_w + (size_t)r * D_ + t * 4);
            const float4 w1 = *(const float4*)(ln_w + (size_t)r * D_ + 1024 + t * 4);
            const float4 b0 = *(const float4*)(ln_b + (size_t)r * D_ + t * 4);
            const float4 b1 = *(const float4*)(ln_b + (size_t)r * D_ + 1024 + t * 4);
            wreg[r][0] = make_ushort4(f2bf(w0.x), f2bf(w0.y), f2bf(w0.z), f2bf(w0.w));
            wreg[r][1] = make_ushort4(f2bf(w1.x), f2bf(w1.y), f2bf(w1.z), f2bf(w1.w));
            breg[r][0] = make_ushort4(f2bf(b0.x), f2bf(b0.y), f2bf(b0.z), f2bf(b0.w));
            breg[r][1] = make_ushort4(f2bf(b1.x), f2bf(b1.y), f2bf(b1.z), f2bf(b1.w));
        }

        // batch-read all 8 rows (kept in regs; re-used in store phase)
        float4 v0s[8], v1s[8];
        #pragma unroll
        for (int rr = 0; rr < 8; ++rr) {
            const float* xr = x + (size_t)(n0 + rr) * D_;
            v0s[rr] = *(const float4*)(xr + t * 4);
            v1s[rr] = *(const float4*)(xr + 1024 + t * 4);
        }

        // per-row wave reduction -> per-row sm slots (no reuse hazard)
        #pragma unroll
        for (int rr = 0; rr < 8; ++rr) {
            const float4 v0 = v0s[rr], v1 = v1s[rr];
            float s  = v0.x + v0.y + v0.z + v0.w + v1.x + v1.y + v1.z + v1.w;
            float sq = v0.x*v0.x + v0.y*v0.y + v0.z*v0.z + v0.w*v0.w
                     + v1.x*v1.x + v1.y*v1.y + v1.z*v1.z + v1.w*v1.w;
            #pragma unroll
            for (int o = 32; o > 0; o >>= 1) {
                s  += __shfl_xor(s,  o, 64);
                sq += __shfl_xor(sq, o, 64);
            }
            if ((t & 63) == 0) {
                sm[rr * 4 + wid]      = s;
                sm[32 + rr * 4 + wid] = sq;
            }
        }
        __syncthreads();                     // the ONLY barrier

        float mean_[8], rstd_[8];
        #pragma unroll
        for (int rr = 0; rr < 8; ++rr) {
            const float s  = sm[rr*4] + sm[rr*4+1] + sm[rr*4+2] + sm[rr*4+3];
            const float sq = sm[32+rr*4] + sm[32+rr*4+1] + sm[32+rr*4+2] + sm[32+rr*4+3];
            mean_[rr] = s * (1.0f / D_);
            const float var = sq * (1.0f / D_) - mean_[rr] * mean_[rr];
            rstd_[rr] = rsqrtf(var + LN_EPS);
        }

        // store phase: barrier-free; NT acks stay in flight to kernel end
        #pragma unroll
        for (int rr = 0; rr < 8; ++rr) {
            const int n = n0 + rr;
            const float mean = mean_[rr], rstd = rstd_[rr];
            float4 h0, h1;
            h0.x = (v0s[rr].x - mean) * rstd; h0.y = (v0s[rr].y - mean) * rstd;
            h0.z = (v0s[rr].z - mean) * rstd; h0.w = (v0s[rr].w - mean) * rstd;
            h1.x = (v1s[rr].x - mean) * rstd; h1.y = (v1s[rr].y - mean) * rstd;
            h1.z = (v1s[rr].z - mean) * rstd; h1.w = (v1s[rr].w - mean) * rstd;

            ushort4 p0 = make_ushort4(f2bf(h0.x), f2bf(h0.y), f2bf(h0.z), f2bf(h0.w));
            ushort4 p1 = make_ushort4(f2bf(h1.x), f2bf(h1.y), f2bf(h1.z), f2bf(h1.w));
            *(ushort4*)(xhat + (size_t)n * D_ + t * 4)        = p0;
            *(ushort4*)(xhat + (size_t)n * D_ + 1024 + t * 4) = p1;

            #pragma unroll
            for (int r = 0; r < 8; ++r) {
                f32x4 o0, o1;
                o0[0] = h0.x * bf2f(wreg[r][0].x) + bf2f(breg[r][0].x);
                o0[1] = h0.y * bf2f(wreg[r][0].y) + bf2f(breg[r][0].y);
                o0[2] = h0.z * bf2f(wreg[r][0].z) + bf2f(breg[r][0].z);
                o0[3] = h0.w * bf2f(wreg[r][0].w) + bf2f(breg[r][0].w);
                o1[0] = h1.x * bf2f(wreg[r][1].x) + bf2f(breg[r][1].x);
                o1[1] = h1.y * bf2f(wreg[r][1].y) + bf2f(breg[r][1].y);
                o1[2] = h1.z * bf2f(wreg[r][1].z) + bf2f(breg[r][1].z);
                o1[3] = h1.w * bf2f(wreg[r][1].w) + bf2f(breg[r][1].w);
                float* dst = new_x + ((size_t)r * N_ + n) * D_;
                __builtin_nontemporal_store(o0, (f32x4*)(dst + t * 4));
                __builtin_nontemporal_store(o1, (f32x4*)(dst + 1024 + t * 4));
            }
        }
    } else {
        const int j = blockIdx.x >> 1;       // 0..1023
        const int r = j >> 7, a = j & 127;
        const float* Wc = W + (size_t)r * D_ * A_ + a;

        float vals[8];
        float s = 0.f, sq = 0.f;
        #pragma unroll
        for (int k = 0; k < 8; ++k) {
            float v = Wc[(size_t)(t + k * 256) * A_];
            vals[k] = v; s += v; sq += v * v;
        }
        #pragma unroll
        for (int o = 32; o > 0; o >>= 1) {
            s  += __shfl_xor(s,  o, 64);
            sq += __shfl_xor(sq, o, 64);
        }
        if ((t & 63) == 0) { sm[t >> 6] = s; sm[8 + (t >> 6)] = sq; }
        __syncthreads();
        s  = sm[0] + sm[1] + sm[2] + sm[3];
        sq = sm[8] + sm[9] + sm[10] + sm[11];
        const float mean = s * (1.0f / D_);
        const float var  = sq * (1.0f / D_) - mean * mean;
        const float rstd = rsqrtf(var + LN_EPS);

        float cp = 0.f;
        #pragma unroll
        for (int k = 0; k < 8; ++k) {
            const int d = t + k * 256;
            const float nv = (vals[k] - mean) * rstd * rw_w[(size_t)r * D_ + d]
                           + rw_b[(size_t)r * D_ + d];
            Bt[(size_t)j * D_ + d] = f2bf(ln_w[(size_t)r * D_ + d] * nv);
            cp += ln_b[(size_t)r * D_ + d] * nv;
        }
        __syncthreads();   // sm reuse
        #pragma unroll
        for (int o = 32; o > 0; o >>= 1) cp += __shfl_xor(cp, o, 64);
        if ((t & 63) == 0) sm[t >> 6] = cp;
        __syncthreads();
        if (t == 0) cvec[j] = sm[0] + sm[1] + sm[2] + sm[3] + rbias[(size_t)r * A_ + a];
    }
}

// ---------------------------------------------------------------------------
// k2 (k_gemm): R18's proven form (R19's dbuf cost 6->3 blocks/CU: -17 us).
//   Single-buffer BK=64 + T2 XOR-swizzle, 24 KB LDS (~6 blocks/CU); TLP
//   across blocks hides staging latency. Reads L2 (Bt, router==XCD) /
//   L3 (xhat) hot; epilogue bias + row softmax, NT stores.
// ---------------------------------------------------------------------------
__global__ __launch_bounds__(256) void k_gemm(
    const ushort* __restrict__ Xh,
    const ushort* __restrict__ Bt,
    const float* __restrict__ cvec,
    float* __restrict__ logits,
    float* __restrict__ probs)
{
    __shared__ __attribute__((aligned(16))) ushort As[64 * 64];    // 8 KB
    __shared__ __attribute__((aligned(16))) ushort Bs[128 * 64];   // 16 KB

    const int t    = threadIdx.x;
    const int lane = t & 63;
    const int w    = t >> 6;             // wave 0..3, rows w*16..w*16+15
    const int r    = blockIdx.x & 7;     // router == XCD
    const int mt   = blockIdx.x >> 3;    // m-tile 0..127
    const int m0   = mt * 64;
    const int j0   = r * 128;

    f32x4 acc[8];
    #pragma unroll
    for (int jf = 0; jf < 8; ++jf) acc[jf] = (f32x4){0.f, 0.f, 0.f, 0.f};

    for (int kt = 0; kt < 32; ++kt) {
        __syncthreads();                 // prev iter's LDS reads done
        // stage A: 512 chunks (2/thread); LDS (row,slot) <- global kc=slot^(row&7)
        #pragma unroll
        for (int c = 0; c < 2; ++c) {
            const int q    = t + c * 256;    // 0..511
            const int row  = q >> 3;         // 0..63
            const int slot = q & 7;
            const int kc   = slot ^ (row & 7);
            const ushort* gA = Xh + (size_t)(m0 + row) * D_ + kt * 64 + kc * 8;
            __builtin_amdgcn_global_load_lds(
                (const __attribute__((address_space(1))) void*)gA,
                (__attribute__((address_space(3))) void*)(&As[q * 8]), 16, 0, 0);
        }
        // stage B: 1024 chunks (4/thread)
        #pragma unroll
        for (int c = 0; c < 4; ++c) {
            const int q    = t + c * 256;    // 0..1023
            const int row  = q >> 3;         // 0..127
            const int slot = q & 7;
            const int kc   = slot ^ (row & 7);
            const ushort* gB = Bt + (size_t)(j0 + row) * D_ + kt * 64 + kc * 8;
            __builtin_amdgcn_global_load_lds(
                (const __attribute__((address_space(1))) void*)gB,
                (__attribute__((address_space(3))) void*)(&Bs[q * 8]), 16, 0, 0);
        }
        __syncthreads();                 // staging complete

        // MFMA: wave w rows w*16..+15; 2 k-frags x 8 j-frags, swizzled reads
        #pragma unroll
        for (int kf = 0; kf < 2; ++kf) {
            const int slot  = (lane >> 4) + 4 * kf;
            const int pslot = slot ^ (lane & 7);
            const bf16x8 afr = *(const bf16x8*)(&As[(w * 16 + (lane & 15)) * 64
                                                    + pslot * 8]);
            #pragma unroll
            for (int jf = 0; jf < 8; ++jf) {
                const bf16x8 bfr = *(const bf16x8*)(&Bs[(jf * 16 + (lane & 15)) * 64
                                                        + pslot * 8]);
                acc[jf] = __builtin_amdgcn_mfma_f32_16x16x32_bf16(afr, bfr, acc[jf], 0, 0, 0);
            }
        }
    }

    // Epilogue: bias + row softmax (j-range == router r's full A=128).
    // C/D layout: col = lane&15, row = (lane>>4)*4 + reg.
    float cv[8];
    #pragma unroll
    for (int jf = 0; jf < 8; ++jf) cv[jf] = cvec[j0 + jf * 16 + (lane & 15)];

    #pragma unroll
    for (int reg = 0; reg < 4; ++reg) {
        const int row = m0 + w * 16 + (lane >> 4) * 4 + reg;
        float v[8], e[8];
        float mx = -3.4e38f;
        #pragma unroll
        for (int jf = 0; jf < 8; ++jf) {
            v[jf] = acc[jf][reg] + cv[jf];
            mx = fmaxf(mx, v[jf]);
        }
        #pragma unroll
        for (int o = 8; o > 0; o >>= 1) mx = fmaxf(mx, __shfl_xor(mx, o, 64));
        float ssum = 0.f;
        #pragma unroll
        for (int jf = 0; jf < 8; ++jf) { e[jf] = __expf(v[jf] - mx); ssum += e[jf]; }
        #pragma unroll
        for (int o = 8; o > 0; o >>= 1) ssum += __shfl_xor(ssum, o, 64);
        const float inv = 1.0f / ssum;
        float* lrow = logits + ((size_t)r * N_ + row) * A_;
        float* prow = probs  + ((size_t)r * N_ + row) * A_;
        #pragma unroll
        for (int jf = 0; jf < 8; ++jf) {
            const int aa = jf * 16 + (lane & 15);
            __builtin_nontemporal_store(v[jf], lrow + aa);
            __builtin_nontemporal_store(e[jf] * inv, prow + aa);
        }
    }
}

// ---------------------------------------------------------------------------
extern "C" void kernel_launch(void* const* d_in, const int* in_sizes, int n_in,
                              void* d_out, int out_size, void* d_ws, size_t ws_size,
                              hipStream_t stream)
{
    const float* x     = (const float*)d_in[0];
    const float* ln_w  = (const float*)d_in[1];
    const float* ln_b  = (const float*)d_in[2];
    const float* W     = (const float*)d_in[3];
    const float* rw_w  = (const float*)d_in[4];
    const float* rw_b  = (const float*)d_in[5];
    const float* rbias = (const float*)d_in[6];

    float* out    = (float*)d_out;
    float* new_x  = out;                                   // [R,N,D]
    float* logits = out + (size_t)R_ * N_ * D_;            // [R,N,A]
    float* probs  = logits + (size_t)R_ * N_ * A_;         // [R,N,A]

    // ws: xhat bf16 [N][D] (32 MiB) | Bt bf16 [J][D] (4 MiB) | cvec f32 [J]
    ushort* xhat = (ushort*)d_ws;
    ushort* Btp  = (ushort*)((char*)d_ws + (size_t)N_ * D_ * 2);
    float*  cvec = (float*)((char*)d_ws + (size_t)N_ * D_ * 2 + (size_t)J_ * D_ * 2);

    hipLaunchKernelGGL(k_lnx,  dim3(2048), dim3(256), 0, stream,
                       x, W, ln_w, ln_b, rw_w, rw_b, rbias, xhat, Btp, cvec, new_x);
    hipLaunchKernelGGL(k_gemm, dim3(J_),   dim3(256), 0, stream,
                       xhat, Btp, cvec, logits, probs);
}

// Round 21
// 163.710 us; speedup vs baseline: 1.2473x; 1.2473x over previous
//
#include <hip/hip_runtime.h>
#include <hip/hip_bf16.h>
#include <stdint.h>

#define R_ 8
#define N_ 8192
#define D_ 2048
#define A_ 128
#define J_ 1024          // R_*A_
#define LN_EPS 1e-5f

typedef __attribute__((ext_vector_type(8))) short bf16x8;   // 8 bf16 in 4 VGPRs
typedef __attribute__((ext_vector_type(4))) float f32x4;

__device__ inline ushort f2bf(float f) {
    union { float f; uint32_t u; } v; v.f = f;
    uint32_t u = v.u;
    return (ushort)((u + 0x7fffu + ((u >> 16) & 1u)) >> 16);   // RNE
}
__device__ inline float bf2f(ushort u) {
    union { uint32_t u; float f; } v; v.u = ((uint32_t)u) << 16;
    return v.f;
}

// ---------------------------------------------------------------------------
// k1 (k_lnx): 9216 blocks in groups of 9 (8 x-row blocks + 1 W-col block).
//   x-row block: row-LN stats (fp32 regs) -> xhat row (bf16, plain store:
//   k2 re-reads it via L2/L3) AND all 8 new_x rows directly (fp32, NT,
//   1 KB contiguous per wave op). Pure write stream — R18's -19 us win.
//   R20 lesson: keep blocks THIN (low VGPR, high occupancy) — 8-row
//   batching (144 VGPR, 2% occupancy) collapsed the store stream.
//   W-col block: weight-LN of column j -> Bt (K-major bf16) + cvec.
// ---------------------------------------------------------------------------
__global__ __launch_bounds__(256) void k_lnx(
    const float* __restrict__ x,
    const float* __restrict__ W,
    const float* __restrict__ ln_w,
    const float* __restrict__ ln_b,
    const float* __restrict__ rw_w,
    const float* __restrict__ rw_b,
    const float* __restrict__ rbias,
    ushort* __restrict__ xhat,
    ushort* __restrict__ Bt,
    float* __restrict__ cvec,
    float* __restrict__ new_x)
{
    __shared__ float sm[16];
    const int t = threadIdx.x;
    const int g = blockIdx.x / 9;
    const int i = blockIdx.x % 9;

    if (i < 8) {
        const int n = g * 8 + i;
        const float* xr = x + (size_t)n * D_;
        float4 v0 = *(const float4*)(xr + t * 4);
        float4 v1 = *(const float4*)(xr + 1024 + t * 4);
        float s  = v0.x + v0.y + v0.z + v0.w + v1.x + v1.y + v1.z + v1.w;
        float sq = v0.x*v0.x + v0.y*v0.y + v0.z*v0.z + v0.w*v0.w
                 + v1.x*v1.x + v1.y*v1.y + v1.z*v1.z + v1.w*v1.w;
        #pragma unroll
        for (int o = 32; o > 0; o >>= 1) {
            s  += __shfl_xor(s,  o, 64);
            sq += __shfl_xor(sq, o, 64);
        }
        if ((t & 63) == 0) { sm[t >> 6] = s; sm[8 + (t >> 6)] = sq; }
        __syncthreads();
        s  = sm[0] + sm[1] + sm[2] + sm[3];
        sq = sm[8] + sm[9] + sm[10] + sm[11];
        const float mean = s * (1.0f / D_);
        const float var  = sq * (1.0f / D_) - mean * mean;
        const float rstd = rsqrtf(var + LN_EPS);

        float4 h0, h1;
        h0.x = (v0.x - mean) * rstd; h0.y = (v0.y - mean) * rstd;
        h0.z = (v0.z - mean) * rstd; h0.w = (v0.w - mean) * rstd;
        h1.x = (v1.x - mean) * rstd; h1.y = (v1.y - mean) * rstd;
        h1.z = (v1.z - mean) * rstd; h1.w = (v1.w - mean) * rstd;

        ushort4 p0 = make_ushort4(f2bf(h0.x), f2bf(h0.y), f2bf(h0.z), f2bf(h0.w));
        ushort4 p1 = make_ushort4(f2bf(h1.x), f2bf(h1.y), f2bf(h1.z), f2bf(h1.w));
        *(ushort4*)(xhat + (size_t)n * D_ + t * 4)        = p0;
        *(ushort4*)(xhat + (size_t)n * D_ + 1024 + t * 4) = p1;

        #pragma unroll
        for (int r = 0; r < R_; ++r) {
            const float* wr = ln_w + (size_t)r * D_;
            const float* br = ln_b + (size_t)r * D_;
            const float4 w0 = *(const float4*)(wr + t * 4);
            const float4 b0 = *(const float4*)(br + t * 4);
            const float4 w1 = *(const float4*)(wr + 1024 + t * 4);
            const float4 b1 = *(const float4*)(br + 1024 + t * 4);
            f32x4 o0, o1;
            o0[0] = h0.x * w0.x + b0.x; o0[1] = h0.y * w0.y + b0.y;
            o0[2] = h0.z * w0.z + b0.z; o0[3] = h0.w * w0.w + b0.w;
            o1[0] = h1.x * w1.x + b1.x; o1[1] = h1.y * w1.y + b1.y;
            o1[2] = h1.z * w1.z + b1.z; o1[3] = h1.w * w1.w + b1.w;
            float* dst = new_x + ((size_t)r * N_ + n) * D_;
            __builtin_nontemporal_store(o0, (f32x4*)(dst + t * 4));
            __builtin_nontemporal_store(o1, (f32x4*)(dst + 1024 + t * 4));
        }
    } else {
        const int j = g;
        const int r = j >> 7, a = j & 127;
        const float* Wc = W + (size_t)r * D_ * A_ + a;

        float vals[8];
        float s = 0.f, sq = 0.f;
        #pragma unroll
        for (int k = 0; k < 8; ++k) {
            float v = Wc[(size_t)(t + k * 256) * A_];
            vals[k] = v; s += v; sq += v * v;
        }
        #pragma unroll
        for (int o = 32; o > 0; o >>= 1) {
            s  += __shfl_xor(s,  o, 64);
            sq += __shfl_xor(sq, o, 64);
        }
        if ((t & 63) == 0) { sm[t >> 6] = s; sm[8 + (t >> 6)] = sq; }
        __syncthreads();
        s  = sm[0] + sm[1] + sm[2] + sm[3];
        sq = sm[8] + sm[9] + sm[10] + sm[11];
        const float mean = s * (1.0f / D_);
        const float var  = sq * (1.0f / D_) - mean * mean;
        const float rstd = rsqrtf(var + LN_EPS);

        float cp = 0.f;
        #pragma unroll
        for (int k = 0; k < 8; ++k) {
            const int d = t + k * 256;
            const float nv = (vals[k] - mean) * rstd * rw_w[(size_t)r * D_ + d]
                           + rw_b[(size_t)r * D_ + d];
            Bt[(size_t)j * D_ + d] = f2bf(ln_w[(size_t)r * D_ + d] * nv);
            cp += ln_b[(size_t)r * D_ + d] * nv;
        }
        __syncthreads();   // sm reuse
        #pragma unroll
        for (int o = 32; o > 0; o >>= 1) cp += __shfl_xor(cp, o, 64);
        if ((t & 63) == 0) sm[t >> 6] = cp;
        __syncthreads();
        if (t == 0) cvec[j] = sm[0] + sm[1] + sm[2] + sm[3] + rbias[(size_t)r * A_ + a];
    }
}

// ---------------------------------------------------------------------------
// k2 (k_gemm): R18's proven form. Single-buffer BK=64 + T2 XOR-swizzle,
//   24 KB LDS (~6 blocks/CU); cross-block TLP hides staging latency
//   (R19's explicit dbuf halved occupancy: -17 us). Reads L2 (Bt,
//   router==XCD) / L3 (xhat) hot; epilogue bias + row softmax, NT stores.
// ---------------------------------------------------------------------------
__global__ __launch_bounds__(256) void k_gemm(
    const ushort* __restrict__ Xh,
    const ushort* __restrict__ Bt,
    const float* __restrict__ cvec,
    float* __restrict__ logits,
    float* __restrict__ probs)
{
    __shared__ __attribute__((aligned(16))) ushort As[64 * 64];    // 8 KB
    __shared__ __attribute__((aligned(16))) ushort Bs[128 * 64];   // 16 KB

    const int t    = threadIdx.x;
    const int lane = t & 63;
    const int w    = t >> 6;             // wave 0..3, rows w*16..w*16+15
    const int r    = blockIdx.x & 7;     // router == XCD
    const int mt   = blockIdx.x >> 3;    // m-tile 0..127
    const int m0   = mt * 64;
    const int j0   = r * 128;

    f32x4 acc[8];
    #pragma unroll
    for (int jf = 0; jf < 8; ++jf) acc[jf] = (f32x4){0.f, 0.f, 0.f, 0.f};

    for (int kt = 0; kt < 32; ++kt) {
        __syncthreads();                 // prev iter's LDS reads done
        // stage A: 512 chunks (2/thread); LDS (row,slot) <- global kc=slot^(row&7)
        #pragma unroll
        for (int c = 0; c < 2; ++c) {
            const int q    = t + c * 256;    // 0..511
            const int row  = q >> 3;         // 0..63
            const int slot = q & 7;
            const int kc   = slot ^ (row & 7);
            const ushort* gA = Xh + (size_t)(m0 + row) * D_ + kt * 64 + kc * 8;
            __builtin_amdgcn_global_load_lds(
                (const __attribute__((address_space(1))) void*)gA,
                (__attribute__((address_space(3))) void*)(&As[q * 8]), 16, 0, 0);
        }
        // stage B: 1024 chunks (4/thread)
        #pragma unroll
        for (int c = 0; c < 4; ++c) {
            const int q    = t + c * 256;    // 0..1023
            const int row  = q >> 3;         // 0..127
            const int slot = q & 7;
            const int kc   = slot ^ (row & 7);
            const ushort* gB = Bt + (size_t)(j0 + row) * D_ + kt * 64 + kc * 8;
            __builtin_amdgcn_global_load_lds(
                (const __attribute__((address_space(1))) void*)gB,
                (__attribute__((address_space(3))) void*)(&Bs[q * 8]), 16, 0, 0);
        }
        __syncthreads();                 // staging complete

        // MFMA: wave w rows w*16..+15; 2 k-frags x 8 j-frags, swizzled reads
        #pragma unroll
        for (int kf = 0; kf < 2; ++kf) {
            const int slot  = (lane >> 4) + 4 * kf;
            const int pslot = slot ^ (lane & 7);
            const bf16x8 afr = *(const bf16x8*)(&As[(w * 16 + (lane & 15)) * 64
                                                    + pslot * 8]);
            #pragma unroll
            for (int jf = 0; jf < 8; ++jf) {
                const bf16x8 bfr = *(const bf16x8*)(&Bs[(jf * 16 + (lane & 15)) * 64
                                                        + pslot * 8]);
                acc[jf] = __builtin_amdgcn_mfma_f32_16x16x32_bf16(afr, bfr, acc[jf], 0, 0, 0);
            }
        }
    }

    // Epilogue: bias + row softmax (j-range == router r's full A=128).
    // C/D layout: col = lane&15, row = (lane>>4)*4 + reg.
    float cv[8];
    #pragma unroll
    for (int jf = 0; jf < 8; ++jf) cv[jf] = cvec[j0 + jf * 16 + (lane & 15)];

    #pragma unroll
    for (int reg = 0; reg < 4; ++reg) {
        const int row = m0 + w * 16 + (lane >> 4) * 4 + reg;
        float v[8], e[8];
        float mx = -3.4e38f;
        #pragma unroll
        for (int jf = 0; jf < 8; ++jf) {
            v[jf] = acc[jf][reg] + cv[jf];
            mx = fmaxf(mx, v[jf]);
        }
        #pragma unroll
        for (int o = 8; o > 0; o >>= 1) mx = fmaxf(mx, __shfl_xor(mx, o, 64));
        float ssum = 0.f;
        #pragma unroll
        for (int jf = 0; jf < 8; ++jf) { e[jf] = __expf(v[jf] - mx); ssum += e[jf]; }
        #pragma unroll
        for (int o = 8; o > 0; o >>= 1) ssum += __shfl_xor(ssum, o, 64);
        const float inv = 1.0f / ssum;
        float* lrow = logits + ((size_t)r * N_ + row) * A_;
        float* prow = probs  + ((size_t)r * N_ + row) * A_;
        #pragma unroll
        for (int jf = 0; jf < 8; ++jf) {
            const int aa = jf * 16 + (lane & 15);
            __builtin_nontemporal_store(v[jf], lrow + aa);
            __builtin_nontemporal_store(e[jf] * inv, prow + aa);
        }
    }
}

// ---------------------------------------------------------------------------
extern "C" void kernel_launch(void* const* d_in, const int* in_sizes, int n_in,
                              void* d_out, int out_size, void* d_ws, size_t ws_size,
                              hipStream_t stream)
{
    const float* x     = (const float*)d_in[0];
    const float* ln_w  = (const float*)d_in[1];
    const float* ln_b  = (const float*)d_in[2];
    const float* W     = (const float*)d_in[3];
    const float* rw_w  = (const float*)d_in[4];
    const float* rw_b  = (const float*)d_in[5];
    const float* rbias = (const float*)d_in[6];

    float* out    = (float*)d_out;
    float* new_x  = out;                                   // [R,N,D]
    float* logits = out + (size_t)R_ * N_ * D_;            // [R,N,A]
    float* probs  = logits + (size_t)R_ * N_ * A_;         // [R,N,A]

    // ws: xhat bf16 [N][D] (32 MiB) | Bt bf16 [J][D] (4 MiB) | cvec f32 [J]
    ushort* xhat = (ushort*)d_ws;
    ushort* Btp  = (ushort*)((char*)d_ws + (size_t)N_ * D_ * 2);
    float*  cvec = (float*)((char*)d_ws + (size_t)N_ * D_ * 2 + (size_t)J_ * D_ * 2);

    hipLaunchKernelGGL(k_lnx,  dim3(9 * J_), dim3(256), 0, stream,
                       x, W, ln_w, ln_b, rw_w, rw_b, rbias, xhat, Btp, cvec, new_x);
    hipLaunchKernelGGL(k_gemm, dim3(J_),     dim3(256), 0, stream,
                       xhat, Btp, cvec, logits, probs);
}